// Round 6
// baseline (813.404 us; speedup 1.0000x reference)
//
#include <hip/hip_runtime.h>
#include <hip/hip_bf16.h>
#include <cstdio>

typedef short s16x8 __attribute__((ext_vector_type(8)));
typedef unsigned short u16x8 __attribute__((ext_vector_type(8)));
typedef float f32x4 __attribute__((ext_vector_type(4)));

#define B_TOK 8192
#define DDIM 1024
#define INTER 2816
#define NEXP 8

#define CAP256_TILES 72
#define CAP256_SLOTS (CAP256_TILES * 256)   // 18432
#define CAP128_TILES (CAP256_SLOTS / 128)   // 144
#define CAP_TILES_FB 136                    // fallback (128-aligned regions)
#define CAP_SLOTS_FB (CAP_TILES_FB * 128)   // 17408

#define BK2 64
#define NKT (INTER / BK2)                   // 44
#define KITERS (NKT / 2)                    // 22

__device__ __forceinline__ unsigned short f2bf(float f) {
    unsigned int u = __float_as_uint(f);
    unsigned int r = u + 0x7fffu + ((u >> 16) & 1u);
    return (unsigned short)(r >> 16);
}

__device__ __forceinline__ float bf2f(unsigned short u) {
    unsigned int x = ((unsigned int)u) << 16;
    return __uint_as_float(x);
}

__device__ __forceinline__ void gload_lds16(const void* g, void* l) {
    __builtin_amdgcn_global_load_lds(
        (const __attribute__((address_space(1))) unsigned int*)g,
        (__attribute__((address_space(3))) unsigned int*)l, 16, 0, 0);
}

// ---------------- transpose+convert ----------------
__global__ __launch_bounds__(256) void transpose_convert_v2(
    const float* __restrict__ src, unsigned short* __restrict__ dst,
    int K, int N) {
    __shared__ unsigned short tile[64][70];
    int e = blockIdx.z;
    src += (size_t)e * K * N;
    dst += (size_t)e * K * N;
    int n0 = blockIdx.x * 64, k0 = blockIdx.y * 64;
    int t = threadIdx.x;
    int lr = t >> 4;
    int lc = (t & 15) * 4;
#pragma unroll
    for (int p = 0; p < 4; ++p) {
        int kl = p * 16 + lr;
        float4 v = *(const float4*)(src + (size_t)(k0 + kl) * N + n0 + lc);
        tile[kl][lc + 0] = f2bf(v.x);
        tile[kl][lc + 1] = f2bf(v.y);
        tile[kl][lc + 2] = f2bf(v.z);
        tile[kl][lc + 3] = f2bf(v.w);
    }
    __syncthreads();
    int sn = t >> 3;
    int sk = (t & 7) * 8;
#pragma unroll
    for (int p = 0; p < 2; ++p) {
        int nl = p * 32 + sn;
        u16x8 o;
#pragma unroll
        for (int j = 0; j < 8; ++j) o[j] = tile[sk + j][nl];
        *(u16x8*)(dst + (size_t)(n0 + nl) * K + k0 + sk) = o;
    }
}

// ---------------- gating (fused convert + routing + loss sums) ----------------
__global__ void gating_kernel(const float* __restrict__ h,
                              const float* __restrict__ gw,
                              float* __restrict__ route,
                              int* __restrict__ sel01,
                              float2* __restrict__ wpair,
                              int* __restrict__ counts,
                              float* __restrict__ sums,
                              unsigned short* __restrict__ hb) {
    int wid = threadIdx.x >> 6, lane = threadIdx.x & 63;
    int t = blockIdx.x * 4 + wid;
    const float* hp = h + (size_t)t * DDIM + lane * 16;
    float4 hv[4];
#pragma unroll
    for (int p = 0; p < 4; ++p) hv[p] = ((const float4*)hp)[p];

    u16x8 o0, o1;
    o0[0] = f2bf(hv[0].x); o0[1] = f2bf(hv[0].y); o0[2] = f2bf(hv[0].z); o0[3] = f2bf(hv[0].w);
    o0[4] = f2bf(hv[1].x); o0[5] = f2bf(hv[1].y); o0[6] = f2bf(hv[1].z); o0[7] = f2bf(hv[1].w);
    o1[0] = f2bf(hv[2].x); o1[1] = f2bf(hv[2].y); o1[2] = f2bf(hv[2].z); o1[3] = f2bf(hv[2].w);
    o1[4] = f2bf(hv[3].x); o1[5] = f2bf(hv[3].y); o1[6] = f2bf(hv[3].z); o1[7] = f2bf(hv[3].w);
    unsigned short* hbp = hb + (size_t)t * DDIM + lane * 16;
    *(u16x8*)hbp = o0;
    *(u16x8*)(hbp + 8) = o1;

    const float4* gp4 = (const float4*)(gw + (size_t)lane * 16 * NEXP);
    float s[8] = {0, 0, 0, 0, 0, 0, 0, 0};
#pragma unroll
    for (int p = 0; p < 4; ++p) {
#pragma unroll
        for (int q = 0; q < 4; ++q) {
            int kk = p * 4 + q;
            float hvk = (q == 0) ? hv[p].x : (q == 1) ? hv[p].y : (q == 2) ? hv[p].z : hv[p].w;
            float4 a = gp4[kk * 2], b = gp4[kk * 2 + 1];
            s[0] += hvk * a.x; s[1] += hvk * a.y; s[2] += hvk * a.z; s[3] += hvk * a.w;
            s[4] += hvk * b.x; s[5] += hvk * b.y; s[6] += hvk * b.z; s[7] += hvk * b.w;
        }
    }
#pragma unroll
    for (int off = 32; off > 0; off >>= 1) {
#pragma unroll
        for (int e = 0; e < 8; ++e) s[e] += __shfl_down(s[e], off);
    }
    if (lane == 0) {
        float m0 = -1e30f; int i0 = 0;
#pragma unroll
        for (int e = 0; e < 8; ++e) if (s[e] > m0) { m0 = s[e]; i0 = e; }
        float m1 = -1e30f; int i1 = -1;
#pragma unroll
        for (int e = 0; e < 8; ++e) if (e != i0 && s[e] > m1) { m1 = s[e]; i1 = e; }
        float d = __expf(m1 - m0);
        float w0 = 1.f / (1.f + d);
        float w1 = d * w0;
#pragma unroll
        for (int e = 0; e < 8; ++e)
            route[(size_t)t * 8 + e] = (e == i0) ? w0 : ((e == i1) ? w1 : 0.f);
        sel01[t] = i0 | (i1 << 8);
        wpair[t] = make_float2(w0, w1);
        atomicAdd(&counts[i0], 1);
        atomicAdd(&counts[i1], 1);
        atomicAdd(&sums[i0], w0);
        atomicAdd(&sums[i1], w1);
    }
}

// setup: per-expert aligned regions + 128-tile table + 256-tile table + lb finalize
__global__ void setup_kernel(const int* __restrict__ counts,
                             const float* __restrict__ sums,
                             int* __restrict__ aoff,
                             int* __restrict__ tile_e,
                             int* __restrict__ tile_s0,
                             int* __restrict__ t2_e,
                             int* __restrict__ t2_s0,
                             float* __restrict__ lb,
                             int algn_shift) {
    __shared__ int s_aoff[8], s_t0[9], s_t2[9];
    if (threadIdx.x == 0) {
        int acc_slot = 0, acc_t = 0, acc_t2 = 0;
        int am = (1 << algn_shift) - 1;
        for (int e = 0; e < 8; ++e) {
            s_aoff[e] = acc_slot;
            s_t0[e] = acc_t;
            s_t2[e] = acc_t2;
            int region = ((counts[e] + am) >> algn_shift) << algn_shift;
            acc_slot += region;
            acc_t += region >> 7;
            acc_t2 += region >> 8;
            aoff[e] = s_aoff[e];
        }
        s_t0[8] = acc_t;
        s_t2[8] = acc_t2;
        float a2 = 0.f;
        for (int e = 0; e < 8; ++e) { float p = sums[e] / (float)B_TOK; a2 += p * p; }
        lb[0] = 0.01f * a2;
    }
    __syncthreads();
    int t = threadIdx.x;
    if (t < CAP128_TILES) {
        int e = -1, s0 = 0;
        for (int x = 0; x < 8; ++x)
            if (t >= s_t0[x] && t < s_t0[x + 1]) { e = x; s0 = s_aoff[x] + ((t - s_t0[x]) << 7); }
        tile_e[t] = e;
        tile_s0[t] = s0;
    }
    if (t < CAP256_TILES) {
        int e = -1, s0 = 0;
        for (int x = 0; x < 8; ++x)
            if (t >= s_t2[x] && t < s_t2[x + 1]) { e = x; s0 = s_aoff[x] + ((t - s_t2[x]) << 8); }
        t2_e[t] = e;
        t2_s0[t] = s0;
    }
}

__global__ void fill_kernel(const int* __restrict__ sel01,
                            const int* __restrict__ aoff,
                            int* __restrict__ rank,
                            int* __restrict__ idx,
                            int2* __restrict__ tslot) {
    int t = blockIdx.x * 256 + threadIdx.x;
    if (t >= B_TOK) return;
    int s = sel01[t];
    int e0 = s & 0xff, e1 = (s >> 8) & 0xff;
    int p0 = atomicAdd(&rank[e0], 1);
    int sl0 = aoff[e0] + p0;
    idx[sl0] = t;
    int p1 = atomicAdd(&rank[e1], 1);
    int sl1 = aoff[e1] + p1;
    idx[sl1] = t;
    tslot[t] = make_int2(sl0, sl1);
}

// ---------------- GEMM1 sparse (m97-style, proven) ----------------
__global__ __launch_bounds__(256, 2) void gemm1_sparse(
    const unsigned short* __restrict__ A,
    const unsigned short* __restrict__ Bg,
    const unsigned short* __restrict__ Bu,
    const int* __restrict__ tile_e,
    const int* __restrict__ tile_s0,
    const int* __restrict__ idx,
    unsigned short* __restrict__ act) {
    int e = tile_e[blockIdx.x];
    if (e < 0) return;
    const int slot0 = tile_s0[blockIdx.x];
    Bg += (size_t)e * DDIM * INTER;
    Bu += (size_t)e * DDIM * INTER;

    __shared__ unsigned short sA[128 * 32];
    __shared__ unsigned short sG[128 * 32];
    __shared__ unsigned short sU[128 * 32];
    const int tid = threadIdx.x, wid = tid >> 6, lane = tid & 63;
    const int wr = wid >> 1, wc = wid & 1;
    const int colBase = blockIdx.y * 128;

    f32x4 accG[4][4], accU[4][4];
#pragma unroll
    for (int i = 0; i < 4; ++i)
#pragma unroll
        for (int j = 0; j < 4; ++j) { accG[i][j] = (f32x4)(0.f); accU[i][j] = (f32x4)(0.f); }

    const int c0 = wid, c1 = wid + 4;
    const int srow = lane >> 2;
    const int skoff = (lane & 3) * 8;
    const int rA = (lane & 15) * 32 + (lane >> 4) * 8;

    const size_t gA0 = (size_t)idx[slot0 + c0 * 16 + srow] * DDIM + skoff;
    const size_t gA1 = (size_t)idx[slot0 + c1 * 16 + srow] * DDIM + skoff;
    const size_t gB0 = (size_t)(colBase + c0 * 16 + srow) * DDIM + skoff;
    const size_t gB1 = (size_t)(colBase + c1 * 16 + srow) * DDIM + skoff;

    for (int k0 = 0; k0 < DDIM; k0 += 32) {
        gload_lds16(A + gA0 + k0, sA + c0 * 512);
        gload_lds16(A + gA1 + k0, sA + c1 * 512);
        gload_lds16(Bg + gB0 + k0, sG + c0 * 512);
        gload_lds16(Bg + gB1 + k0, sG + c1 * 512);
        gload_lds16(Bu + gB0 + k0, sU + c0 * 512);
        gload_lds16(Bu + gB1 + k0, sU + c1 * 512);
        asm volatile("s_waitcnt vmcnt(0)" ::: "memory");
        __syncthreads();

        s16x8 a[4], bg[4], bu[4];
#pragma unroll
        for (int mf = 0; mf < 4; ++mf)
            a[mf] = *(const s16x8*)&sA[(wr * 64 + mf * 16) * 32 + rA];
#pragma unroll
        for (int nf = 0; nf < 4; ++nf) {
            bg[nf] = *(const s16x8*)&sG[(wc * 64 + nf * 16) * 32 + rA];
            bu[nf] = *(const s16x8*)&sU[(wc * 64 + nf * 16) * 32 + rA];
        }
#pragma unroll
        for (int mf = 0; mf < 4; ++mf)
#pragma unroll
            for (int nf = 0; nf < 4; ++nf) {
                accG[mf][nf] = __builtin_amdgcn_mfma_f32_16x16x32_bf16(a[mf], bg[nf], accG[mf][nf], 0, 0, 0);
                accU[mf][nf] = __builtin_amdgcn_mfma_f32_16x16x32_bf16(a[mf], bu[nf], accU[mf][nf], 0, 0, 0);
            }
        __syncthreads();
    }

#pragma unroll
    for (int mf = 0; mf < 4; ++mf)
#pragma unroll
        for (int nf = 0; nf < 4; ++nf)
#pragma unroll
            for (int j = 0; j < 4; ++j) {
                int r = slot0 + wr * 64 + mf * 16 + (lane >> 4) * 4 + j;
                int c = colBase + wc * 64 + nf * 16 + (lane & 15);
                float g = accG[mf][nf][j], u = accU[mf][nf][j];
                float sg = 1.f / (1.f + __expf(-g));
                act[(size_t)r * INTER + c] = f2bf(g * sg * u);
            }
}

// ---------------- GEMM2 8-phase 256x256, BK=64, 512 threads ----------------
// A: act [CAP256_SLOTS][2816], B: wdT [E][1024][2816], y: [CAP256_SLOTS][1024] bf16
// LDS ring: 2 slots x {Ah0,Ah1,Bh0,Bh1} halves of 16 KiB. Halves are PERMUTED:
//   Ah: tile rows {h*64..h*64+63} u {128+h*64..128+h*64+63}
//   Bh: tile cols {q*64+h*32..+31 : q=0..3}
// so phase q=(mh,nh) consumes exactly A-half mh and B-half nh.
// Stage order per K-tile kt: P0:Ah1(kt+1) P1:Bh1(kt+1) P2:Ah0(kt+2) P3:Bh0(kt+2)
// -> every overwrite is >=1 barrier after the region's last read; every read is
// >=4 phases after its stage; vmcnt(6) per phase covers all RAW hazards.
// Bank swizzle: LDS byte (lr*128 + kb) holds global column (kb ^ ((lr&7)<<4)).
__global__ __launch_bounds__(512, 2) void gemm2_8ph(
    const unsigned short* __restrict__ A,
    const unsigned short* __restrict__ Bd,
    const int* __restrict__ t2_e,
    const int* __restrict__ t2_s0,
    unsigned short* __restrict__ y) {
    int e = t2_e[blockIdx.x];
    if (e < 0) return;
    const int m0 = t2_s0[blockIdx.x];
    const int cb = blockIdx.y * 256;
    const unsigned short* Bp = Bd + ((size_t)e * DDIM + cb) * INTER;

    __shared__ unsigned short lds[65536];  // 128 KiB

    const int tid = threadIdx.x, w = tid >> 6, l = tid & 63;
    const int wr = w >> 2, wc = w & 3;
    const int l3 = l >> 3;
    const int kus = ((l & 7) * 8) ^ (l3 << 3);  // swizzled source col (ushorts)

    f32x4 acc[8][4];
#pragma unroll
    for (int i = 0; i < 8; ++i)
#pragma unroll
        for (int j = 0; j < 4; ++j) acc[i][j] = (f32x4)(0.f);

    // per-thread staging row indices (instr j=0,1)
    int lrj[2], rowA[2][2], rowB[2][2];
#pragma unroll
    for (int j = 0; j < 2; ++j) {
        lrj[j] = (j * 8 + w) * 8 + l3;
#pragma unroll
        for (int h = 0; h < 2; ++h) {
            rowA[j][h] = ((lrj[j] >> 6) << 7) + h * 64 + (lrj[j] & 63);
            rowB[j][h] = ((lrj[j] >> 5) << 6) + h * 32 + (lrj[j] & 31);
        }
    }

#define STAGE_A(slot, h, kt)                                                      \
    {                                                                             \
        _Pragma("unroll") for (int j = 0; j < 2; ++j) {                           \
            gload_lds16(A + (size_t)(m0 + rowA[j][h]) * INTER + (kt)*BK2 + kus,   \
                        (void*)(lds + (slot)*32768 + (h)*8192 + (j * 8 + w) * 512)); \
        }                                                                         \
    }
#define STAGE_B(slot, h, kt)                                                      \
    {                                                                             \
        _Pragma("unroll") for (int j = 0; j < 2; ++j) {                           \
            gload_lds16(Bp + (size_t)rowB[j][h] * INTER + (kt)*BK2 + kus,         \
                        (void*)(lds + (slot)*32768 + 16384 + (h)*8192 + (j * 8 + w) * 512)); \
        }                                                                         \
    }

    // prologue: Ah0(0) Bh0(0) Ah1(0) Bh1(0) Ah0(1) Bh0(1)
    STAGE_A(0, 0, 0); STAGE_B(0, 0, 0); STAGE_A(0, 1, 0); STAGE_B(0, 1, 0);
    STAGE_A(1, 0, 1); STAGE_B(1, 0, 1);
    asm volatile("s_waitcnt vmcnt(8)" ::: "memory");
    __builtin_amdgcn_s_barrier();

    const int l15 = l & 15;
    const int kbase = (l >> 4) * 8;  // ushort offset of this lane's 16B within 64-col row

    for (int it = 0; it < KITERS; ++it) {
        const bool notlast = (it < KITERS - 1);
#pragma unroll
        for (int ph = 0; ph < 8; ++ph) {
            const int slot = ph >> 2;
            const int q = ph & 3;
            const int mh = q >> 1, nh = q & 1;
            const int kt = 2 * it + slot;

            s16x8 af[4][2], bf[2][2];
#pragma unroll
            for (int i = 0; i < 4; ++i) {
                int lr = wr * 64 + i * 16 + l15;
                int base = slot * 32768 + mh * 8192 + lr * 64;
                int sw = (lr & 7) << 3;
#pragma unroll
                for (int kk = 0; kk < 2; ++kk)
                    af[i][kk] = *(const s16x8*)&lds[base + ((kk * 32 + kbase) ^ sw)];
            }
#pragma unroll
            for (int i = 0; i < 2; ++i) {
                int ln = wc * 32 + i * 16 + l15;
                int base = slot * 32768 + 16384 + nh * 8192 + ln * 64;
                int sw = (ln & 7) << 3;
#pragma unroll
                for (int kk = 0; kk < 2; ++kk)
                    bf[i][kk] = *(const s16x8*)&lds[base + ((kk * 32 + kbase) ^ sw)];
            }

            if (q == 0) {
                if (slot == 0) { STAGE_A(1, 1, kt + 1); }
                else if (notlast) { STAGE_A(0, 1, kt + 1); }
            } else if (q == 1) {
                if (slot == 0) { STAGE_B(1, 1, kt + 1); }
                else if (notlast) { STAGE_B(0, 1, kt + 1); }
            } else if (q == 2) {
                if (notlast) { STAGE_A(slot, 0, kt + 2); }
            } else {
                if (notlast) { STAGE_B(slot, 0, kt + 2); }
            }

            asm volatile("s_waitcnt vmcnt(6)" ::: "memory");
            __builtin_amdgcn_s_barrier();
            asm volatile("s_waitcnt lgkmcnt(0)" ::: "memory");
            __builtin_amdgcn_sched_barrier(0);
            __builtin_amdgcn_s_setprio(1);
#pragma unroll
            for (int i = 0; i < 4; ++i)
#pragma unroll
                for (int jn = 0; jn < 2; ++jn)
#pragma unroll
                    for (int kk = 0; kk < 2; ++kk)
                        acc[mh * 4 + i][nh * 2 + jn] = __builtin_amdgcn_mfma_f32_16x16x32_bf16(
                            af[i][kk], bf[jn][kk], acc[mh * 4 + i][nh * 2 + jn], 0, 0, 0);
            __builtin_amdgcn_s_setprio(0);
            __builtin_amdgcn_sched_barrier(0);
            __builtin_amdgcn_s_barrier();
        }
    }

#pragma unroll
    for (int i = 0; i < 8; ++i)
#pragma unroll
        for (int jn = 0; jn < 4; ++jn)
#pragma unroll
            for (int r4 = 0; r4 < 4; ++r4) {
                int row = wr * 128 + i * 16 + (l >> 4) * 4 + r4;
                int col = cb + wc * 64 + jn * 16 + l15;
                y[(size_t)(m0 + row) * DDIM + col] = f2bf(acc[i][jn][r4]);
            }
#undef STAGE_A
#undef STAGE_B
}

// ---------------- GEMM2 v3 (fallback, proven round 5) ----------------
__global__ __launch_bounds__(256, 3) void gemm2_sparse_v3(
    const unsigned short* __restrict__ A,
    const unsigned short* __restrict__ Bd,
    const int* __restrict__ tile_e,
    const int* __restrict__ tile_s0,
    unsigned short* __restrict__ y) {
    int e = tile_e[blockIdx.x];
    if (e < 0) return;
    const int slot0 = tile_s0[blockIdx.x];
    const int colBase = blockIdx.y * 128;
    Bd += (size_t)e * DDIM * INTER;

    __shared__ unsigned short sA[128 * 32];
    __shared__ unsigned short sB[128 * 32];
    const int tid = threadIdx.x, wid = tid >> 6, lane = tid & 63;
    const int wr = wid >> 1, wc = wid & 1;

    f32x4 acc[4][4];
#pragma unroll
    for (int i = 0; i < 4; ++i)
#pragma unroll
        for (int j = 0; j < 4; ++j) acc[i][j] = (f32x4)(0.f);

    const int c0 = wid, c1 = wid + 4;
    const int srow = lane >> 2;
    const int skoff = (lane & 3) * 8;
    const int rA = (lane & 15) * 32 + (lane >> 4) * 8;

    const size_t gA0 = (size_t)(slot0 + c0 * 16 + srow) * INTER + skoff;
    const size_t gA1 = (size_t)(slot0 + c1 * 16 + srow) * INTER + skoff;
    const size_t gB0 = (size_t)(colBase + c0 * 16 + srow) * INTER + skoff;
    const size_t gB1 = (size_t)(colBase + c1 * 16 + srow) * INTER + skoff;

    for (int k0 = 0; k0 < INTER; k0 += 32) {
        gload_lds16(A + gA0 + k0, sA + c0 * 512);
        gload_lds16(A + gA1 + k0, sA + c1 * 512);
        gload_lds16(Bd + gB0 + k0, sB + c0 * 512);
        gload_lds16(Bd + gB1 + k0, sB + c1 * 512);
        asm volatile("s_waitcnt vmcnt(0)" ::: "memory");
        __syncthreads();

        s16x8 a[4], b[4];
#pragma unroll
        for (int mf = 0; mf < 4; ++mf)
            a[mf] = *(const s16x8*)&sA[(wr * 64 + mf * 16) * 32 + rA];
#pragma unroll
        for (int nf = 0; nf < 4; ++nf)
            b[nf] = *(const s16x8*)&sB[(wc * 64 + nf * 16) * 32 + rA];
#pragma unroll
        for (int mf = 0; mf < 4; ++mf)
#pragma unroll
            for (int nf = 0; nf < 4; ++nf)
                acc[mf][nf] = __builtin_amdgcn_mfma_f32_16x16x32_bf16(a[mf], b[nf], acc[mf][nf], 0, 0, 0);
        __syncthreads();
    }

#pragma unroll
    for (int mf = 0; mf < 4; ++mf)
#pragma unroll
        for (int j = 0; j < 4; ++j) {
            int slot = slot0 + wr * 64 + mf * 16 + (lane >> 4) * 4 + j;
#pragma unroll
            for (int nf = 0; nf < 4; ++nf) {
                int c = colBase + wc * 64 + nf * 16 + (lane & 15);
                y[(size_t)slot * DDIM + c] = f2bf(acc[mf][nf][j]);
            }
        }
}

// out[t][c] = w0*y[sl0][c] + w1*y[sl1][c]
__global__ __launch_bounds__(256) void combine_kernel(
    const unsigned short* __restrict__ y,
    const int2* __restrict__ tslot,
    const float2* __restrict__ wpair,
    float* __restrict__ out) {
    int gid = blockIdx.x * 256 + threadIdx.x;
    int tok = gid >> 7;
    int c8 = (gid & 127) * 8;
    int2 ts = tslot[tok];
    float2 w = wpair[tok];
    u16x8 a = *(const u16x8*)(y + (size_t)ts.x * DDIM + c8);
    u16x8 b = *(const u16x8*)(y + (size_t)ts.y * DDIM + c8);
    float4 r0, r1;
    r0.x = w.x * bf2f(a[0]) + w.y * bf2f(b[0]);
    r0.y = w.x * bf2f(a[1]) + w.y * bf2f(b[1]);
    r0.z = w.x * bf2f(a[2]) + w.y * bf2f(b[2]);
    r0.w = w.x * bf2f(a[3]) + w.y * bf2f(b[3]);
    r1.x = w.x * bf2f(a[4]) + w.y * bf2f(b[4]);
    r1.y = w.x * bf2f(a[5]) + w.y * bf2f(b[5]);
    r1.z = w.x * bf2f(a[6]) + w.y * bf2f(b[6]);
    r1.w = w.x * bf2f(a[7]) + w.y * bf2f(b[7]);
    float* op = out + (size_t)tok * DDIM + c8;
    *(float4*)op = r0;
    *(float4*)(op + 4) = r1;
}

// ---------------- host ----------------

extern "C" void kernel_launch(void* const* d_in, const int* in_sizes, int n_in,
                              void* d_out, int out_size, void* d_ws, size_t ws_size,
                              hipStream_t stream) {
    const float* h = (const float*)d_in[0];
    const float* gate_w = (const float*)d_in[1];
    const float* wg = (const float*)d_in[2];
    const float* wu = (const float*)d_in[3];
    const float* wd = (const float*)d_in[4];

    float* out = (float*)d_out;
    float* lb = out + (size_t)B_TOK * DDIM;
    float* route = lb + 1;

    const size_t SZ_META = 1 << 20;
    const size_t SZ_HB = (size_t)B_TOK * DDIM * 2;
    const size_t SZ_W = (size_t)NEXP * DDIM * INTER * 2;
    const size_t SZ_ACT256 = (size_t)CAP256_SLOTS * INTER * 2;  // 103.8 MB
    const size_t SZ_ACT_FB = (size_t)CAP_SLOTS_FB * INTER * 2;  // 98.0 MB
    const size_t NEED256 = SZ_META + SZ_HB + 2 * SZ_W + SZ_ACT256;  // ~204 MiB
    const size_t NEED_FB = SZ_META + SZ_HB + 2 * SZ_W + SZ_ACT_FB;  // ~198.5 MiB
    const bool big = (ws_size >= NEED256);
    if (!big && ws_size < NEED_FB) {
        fprintf(stderr, "kernel_launch: ws too small: %zu < %zu\n", ws_size, NEED_FB);
        return;
    }
    char* ws = (char*)d_ws;
    int* counts = (int*)(ws + 0);
    int* rank = (int*)(ws + 32);
    int* aoff = (int*)(ws + 64);
    float* sums = (float*)(ws + 96);
    int* tile_e = (int*)(ws + 128);       // 144
    int* tile_s0 = (int*)(ws + 768);      // 144
    int* t2_e = (int*)(ws + 1344);        // 72
    int* t2_s0 = (int*)(ws + 1632);       // 72
    int* sel01 = (int*)(ws + 2048);       // 8192
    float2* wpair = (float2*)(ws + 34816);
    int* idx = (int*)(ws + 100352);       // up to 18432
    int2* tslot = (int2*)(ws + 174080);   // 8192

    unsigned short* hb = (unsigned short*)(ws + SZ_META);
    unsigned short* wgT = (unsigned short*)(ws + SZ_META + SZ_HB);
    unsigned short* wuT = (unsigned short*)(ws + SZ_META + SZ_HB + SZ_W);
    unsigned short* act = (unsigned short*)(ws + SZ_META + SZ_HB + 2 * SZ_W);
    unsigned short* wdT = wgT;  // reuse after gemm1
    unsigned short* y = wuT;    // reuse after gemm1 (<=37.7MB < 44MB)

    hipMemsetAsync(ws, 0, SZ_META, stream);

    transpose_convert_v2<<<dim3(INTER / 64, DDIM / 64, NEXP), 256, 0, stream>>>(wg, wgT, DDIM, INTER);
    transpose_convert_v2<<<dim3(INTER / 64, DDIM / 64, NEXP), 256, 0, stream>>>(wu, wuT, DDIM, INTER);

    gating_kernel<<<B_TOK / 4, 256, 0, stream>>>(h, gate_w, route, sel01, wpair, counts, sums, hb);
    setup_kernel<<<1, 256, 0, stream>>>(counts, sums, aoff, tile_e, tile_s0, t2_e, t2_s0, lb,
                                        big ? 8 : 7);
    fill_kernel<<<B_TOK / 256, 256, 0, stream>>>(sel01, aoff, rank, idx, tslot);

    gemm1_sparse<<<dim3(big ? CAP128_TILES : CAP_TILES_FB, INTER / 128), 256, 0, stream>>>(
        hb, wgT, wuT, tile_e, tile_s0, idx, act);

    transpose_convert_v2<<<dim3(DDIM / 64, INTER / 64, NEXP), 256, 0, stream>>>(wd, wdT, INTER, DDIM);

    if (big) {
        gemm2_8ph<<<dim3(CAP256_TILES, DDIM / 256), 512, 0, stream>>>(act, wdT, t2_e, t2_s0, y);
    } else {
        gemm2_sparse_v3<<<dim3(CAP_TILES_FB, DDIM / 128), 256, 0, stream>>>(act, wdT, tile_e, tile_s0, y);
    }

    combine_kernel<<<(B_TOK * 128) / 256, 256, 0, stream>>>(y, tslot, wpair, out);
}

// Round 8
// 802.790 us; speedup vs baseline: 1.0132x; 1.0132x over previous
//
#include <hip/hip_runtime.h>
#include <hip/hip_bf16.h>
#include <cstdio>

typedef short s16x8 __attribute__((ext_vector_type(8)));
typedef unsigned short u16x8 __attribute__((ext_vector_type(8)));
typedef float f32x4 __attribute__((ext_vector_type(4)));

#define B_TOK 8192      // b*l
#define DDIM 1024
#define INTER 2816
#define NEXP 8
#define CAP_TILES 136               // max sum ceil(cnt[e]/128) = 135; capacity 136
#define CAP_SLOTS (CAP_TILES * 128) // 17408

__device__ __forceinline__ unsigned short f2bf(float f) {
    unsigned int u = __float_as_uint(f);
    unsigned int r = u + 0x7fffu + ((u >> 16) & 1u);
    return (unsigned short)(r >> 16);
}

__device__ __forceinline__ float bf2f(unsigned short u) {
    unsigned int x = ((unsigned int)u) << 16;
    return __uint_as_float(x);
}

__device__ __forceinline__ void gload_lds16(const void* g, void* l) {
    __builtin_amdgcn_global_load_lds(
        (const __attribute__((address_space(1))) unsigned int*)g,
        (__attribute__((address_space(3))) unsigned int*)l, 16, 0, 0);
}

// ---------------- transpose+convert ----------------
// src: K x N f32 row-major (per expert via z), dst: N x K bf16. 64x64 tiles.
__global__ __launch_bounds__(256) void transpose_convert_v2(
    const float* __restrict__ src, unsigned short* __restrict__ dst,
    int K, int N) {
    __shared__ unsigned short tile[64][70];
    int e = blockIdx.z;
    src += (size_t)e * K * N;
    dst += (size_t)e * K * N;
    int n0 = blockIdx.x * 64, k0 = blockIdx.y * 64;
    int t = threadIdx.x;
    int lr = t >> 4;          // 0..15
    int lc = (t & 15) * 4;    // 0..60
#pragma unroll
    for (int p = 0; p < 4; ++p) {
        int kl = p * 16 + lr;
        float4 v = *(const float4*)(src + (size_t)(k0 + kl) * N + n0 + lc);
        tile[kl][lc + 0] = f2bf(v.x);
        tile[kl][lc + 1] = f2bf(v.y);
        tile[kl][lc + 2] = f2bf(v.z);
        tile[kl][lc + 3] = f2bf(v.w);
    }
    __syncthreads();
    int sn = t >> 3;          // 0..31
    int sk = (t & 7) * 8;     // 0..56
#pragma unroll
    for (int p = 0; p < 2; ++p) {
        int nl = p * 32 + sn;
        u16x8 o;
#pragma unroll
        for (int j = 0; j < 8; ++j) o[j] = tile[sk + j][nl];
        *(u16x8*)(dst + (size_t)(n0 + nl) * K + k0 + sk) = o;
    }
}

// ---------------- gating (fused: bf16-convert of h, routing, loss sums) -------
__global__ void gating_kernel(const float* __restrict__ h,
                              const float* __restrict__ gw,
                              float* __restrict__ route,
                              int* __restrict__ sel01,
                              float2* __restrict__ wpair,
                              int* __restrict__ counts,
                              float* __restrict__ sums,
                              unsigned short* __restrict__ hb) {
    int wid = threadIdx.x >> 6, lane = threadIdx.x & 63;
    int t = blockIdx.x * 4 + wid;
    const float* hp = h + (size_t)t * DDIM + lane * 16;
    float4 hv[4];
#pragma unroll
    for (int p = 0; p < 4; ++p) hv[p] = ((const float4*)hp)[p];

    u16x8 o0, o1;
    o0[0] = f2bf(hv[0].x); o0[1] = f2bf(hv[0].y); o0[2] = f2bf(hv[0].z); o0[3] = f2bf(hv[0].w);
    o0[4] = f2bf(hv[1].x); o0[5] = f2bf(hv[1].y); o0[6] = f2bf(hv[1].z); o0[7] = f2bf(hv[1].w);
    o1[0] = f2bf(hv[2].x); o1[1] = f2bf(hv[2].y); o1[2] = f2bf(hv[2].z); o1[3] = f2bf(hv[2].w);
    o1[4] = f2bf(hv[3].x); o1[5] = f2bf(hv[3].y); o1[6] = f2bf(hv[3].z); o1[7] = f2bf(hv[3].w);
    unsigned short* hbp = hb + (size_t)t * DDIM + lane * 16;
    *(u16x8*)hbp = o0;
    *(u16x8*)(hbp + 8) = o1;

    const float4* gp4 = (const float4*)(gw + (size_t)lane * 16 * NEXP);
    float s[8] = {0, 0, 0, 0, 0, 0, 0, 0};
#pragma unroll
    for (int p = 0; p < 4; ++p) {
#pragma unroll
        for (int q = 0; q < 4; ++q) {
            int kk = p * 4 + q;
            float hvk = (q == 0) ? hv[p].x : (q == 1) ? hv[p].y : (q == 2) ? hv[p].z : hv[p].w;
            float4 a = gp4[kk * 2], b = gp4[kk * 2 + 1];
            s[0] += hvk * a.x; s[1] += hvk * a.y; s[2] += hvk * a.z; s[3] += hvk * a.w;
            s[4] += hvk * b.x; s[5] += hvk * b.y; s[6] += hvk * b.z; s[7] += hvk * b.w;
        }
    }
#pragma unroll
    for (int off = 32; off > 0; off >>= 1) {
#pragma unroll
        for (int e = 0; e < 8; ++e) s[e] += __shfl_down(s[e], off);
    }
    if (lane == 0) {
        float m0 = -1e30f; int i0 = 0;
#pragma unroll
        for (int e = 0; e < 8; ++e) if (s[e] > m0) { m0 = s[e]; i0 = e; }
        float m1 = -1e30f; int i1 = -1;
#pragma unroll
        for (int e = 0; e < 8; ++e) if (e != i0 && s[e] > m1) { m1 = s[e]; i1 = e; }
        float d = __expf(m1 - m0);
        float w0 = 1.f / (1.f + d);
        float w1 = d * w0;
#pragma unroll
        for (int e = 0; e < 8; ++e)
            route[(size_t)t * 8 + e] = (e == i0) ? w0 : ((e == i1) ? w1 : 0.f);
        sel01[t] = i0 | (i1 << 8);
        wpair[t] = make_float2(w0, w1);
        atomicAdd(&counts[i0], 1);
        atomicAdd(&counts[i1], 1);
        atomicAdd(&sums[i0], w0);
        atomicAdd(&sums[i1], w1);
    }
}

// single block: per-expert 128-aligned slot offsets + tile table + lb_loss finalize
__global__ void setup_kernel(const int* __restrict__ counts,
                             const float* __restrict__ sums,
                             int* __restrict__ aoff,
                             int* __restrict__ tile_e,
                             int* __restrict__ tile_s0,
                             float* __restrict__ lb) {
    __shared__ int s_aoff[8], s_t0[9];
    if (threadIdx.x == 0) {
        int acc_slot = 0, acc_tile = 0;
        for (int e = 0; e < 8; ++e) {
            s_aoff[e] = acc_slot;
            s_t0[e] = acc_tile;
            int nt = (counts[e] + 127) >> 7;
            acc_slot += nt << 7;
            acc_tile += nt;
        }
        s_t0[8] = acc_tile;
        for (int e = 0; e < 8; ++e) aoff[e] = s_aoff[e];
        float acc = 0.f;
        for (int e = 0; e < 8; ++e) {
            float p = sums[e] / (float)B_TOK;
            acc += p * p;
        }
        lb[0] = 0.01f * acc;
    }
    __syncthreads();
    int t = threadIdx.x;
    if (t < CAP_TILES) {
        int e = -1, s0 = 0;
        for (int x = 0; x < 8; ++x)
            if (t >= s_t0[x] && t < s_t0[x + 1]) { e = x; s0 = s_aoff[x] + ((t - s_t0[x]) << 7); }
        tile_e[t] = e;
        tile_s0[t] = s0;
    }
}

__global__ void fill_kernel(const int* __restrict__ sel01,
                            const int* __restrict__ aoff,
                            int* __restrict__ rank,
                            int* __restrict__ idx,
                            int2* __restrict__ tslot) {
    int t = blockIdx.x * 256 + threadIdx.x;
    if (t >= B_TOK) return;
    int s = sel01[t];
    int e0 = s & 0xff, e1 = (s >> 8) & 0xff;
    int p0 = atomicAdd(&rank[e0], 1);
    int sl0 = aoff[e0] + p0;
    idx[sl0] = t;
    int p1 = atomicAdd(&rank[e1], 1);
    int sl1 = aoff[e1] + p1;
    idx[sl1] = t;
    tslot[t] = make_int2(sl0, sl1);
}

// ---------------- GEMM1 sparse: gathered rows, g/u dual, fused silu ----------------
// colOff splits the N dimension across two dispatches (profiler visibility).
__global__ __launch_bounds__(256, 2) void gemm1_sparse(
    const unsigned short* __restrict__ A,
    const unsigned short* __restrict__ Bg,
    const unsigned short* __restrict__ Bu,
    const int* __restrict__ tile_e,
    const int* __restrict__ tile_s0,
    const int* __restrict__ idx,
    unsigned short* __restrict__ act,
    int colOff) {
    int e = tile_e[blockIdx.x];
    if (e < 0) return;
    const int slot0 = tile_s0[blockIdx.x];
    Bg += (size_t)e * DDIM * INTER;
    Bu += (size_t)e * DDIM * INTER;

    __shared__ unsigned short sA[128 * 32];
    __shared__ unsigned short sG[128 * 32];
    __shared__ unsigned short sU[128 * 32];
    const int tid = threadIdx.x, wid = tid >> 6, lane = tid & 63;
    const int wr = wid >> 1, wc = wid & 1;
    const int colBase = (colOff + blockIdx.y) * 128;

    f32x4 accG[4][4], accU[4][4];
#pragma unroll
    for (int i = 0; i < 4; ++i)
#pragma unroll
        for (int j = 0; j < 4; ++j) { accG[i][j] = (f32x4)(0.f); accU[i][j] = (f32x4)(0.f); }

    const int c0 = wid, c1 = wid + 4;
    const int srow = lane >> 2;
    const int skoff = (lane & 3) * 8;
    const int rA = (lane & 15) * 32 + (lane >> 4) * 8;

    const size_t gA0 = (size_t)idx[slot0 + c0 * 16 + srow] * DDIM + skoff;
    const size_t gA1 = (size_t)idx[slot0 + c1 * 16 + srow] * DDIM + skoff;
    const size_t gB0 = (size_t)(colBase + c0 * 16 + srow) * DDIM + skoff;
    const size_t gB1 = (size_t)(colBase + c1 * 16 + srow) * DDIM + skoff;

    for (int k0 = 0; k0 < DDIM; k0 += 32) {
        gload_lds16(A + gA0 + k0, sA + c0 * 512);
        gload_lds16(A + gA1 + k0, sA + c1 * 512);
        gload_lds16(Bg + gB0 + k0, sG + c0 * 512);
        gload_lds16(Bg + gB1 + k0, sG + c1 * 512);
        gload_lds16(Bu + gB0 + k0, sU + c0 * 512);
        gload_lds16(Bu + gB1 + k0, sU + c1 * 512);
        asm volatile("s_waitcnt vmcnt(0)" ::: "memory");
        __syncthreads();

        s16x8 a[4], bg[4], bu[4];
#pragma unroll
        for (int mf = 0; mf < 4; ++mf)
            a[mf] = *(const s16x8*)&sA[(wr * 64 + mf * 16) * 32 + rA];
#pragma unroll
        for (int nf = 0; nf < 4; ++nf) {
            bg[nf] = *(const s16x8*)&sG[(wc * 64 + nf * 16) * 32 + rA];
            bu[nf] = *(const s16x8*)&sU[(wc * 64 + nf * 16) * 32 + rA];
        }
#pragma unroll
        for (int mf = 0; mf < 4; ++mf)
#pragma unroll
            for (int nf = 0; nf < 4; ++nf) {
                accG[mf][nf] = __builtin_amdgcn_mfma_f32_16x16x32_bf16(a[mf], bg[nf], accG[mf][nf], 0, 0, 0);
                accU[mf][nf] = __builtin_amdgcn_mfma_f32_16x16x32_bf16(a[mf], bu[nf], accU[mf][nf], 0, 0, 0);
            }
        __syncthreads();
    }

#pragma unroll
    for (int mf = 0; mf < 4; ++mf)
#pragma unroll
        for (int nf = 0; nf < 4; ++nf)
#pragma unroll
            for (int j = 0; j < 4; ++j) {
                int r = slot0 + wr * 64 + mf * 16 + (lane >> 4) * 4 + j;
                int c = colBase + wc * 64 + nf * 16 + (lane & 15);
                float g = accG[mf][nf][j], u = accU[mf][nf][j];
                float sg = 1.f / (1.f + __expf(-g));
                act[(size_t)r * INTER + c] = f2bf(g * sg * u);
            }
}

// ---------------- GEMM2 v3: act @ wdT full-width, slot-major bf16 output ----------------
__global__ __launch_bounds__(256, 3) void gemm2_sparse_v3(
    const unsigned short* __restrict__ A,
    const unsigned short* __restrict__ Bd,
    const int* __restrict__ tile_e,
    const int* __restrict__ tile_s0,
    unsigned short* __restrict__ y) {
    int e = tile_e[blockIdx.x];
    if (e < 0) return;
    const int slot0 = tile_s0[blockIdx.x];
    const int colBase = blockIdx.y * 128;
    Bd += (size_t)e * DDIM * INTER;

    __shared__ unsigned short sA[128 * 32];
    __shared__ unsigned short sB[128 * 32];
    const int tid = threadIdx.x, wid = tid >> 6, lane = tid & 63;
    const int wr = wid >> 1, wc = wid & 1;

    f32x4 acc[4][4];
#pragma unroll
    for (int i = 0; i < 4; ++i)
#pragma unroll
        for (int j = 0; j < 4; ++j) acc[i][j] = (f32x4)(0.f);

    const int c0 = wid, c1 = wid + 4;
    const int srow = lane >> 2;
    const int skoff = (lane & 3) * 8;
    const int rA = (lane & 15) * 32 + (lane >> 4) * 8;

    const size_t gA0 = (size_t)(slot0 + c0 * 16 + srow) * INTER + skoff;
    const size_t gA1 = (size_t)(slot0 + c1 * 16 + srow) * INTER + skoff;
    const size_t gB0 = (size_t)(colBase + c0 * 16 + srow) * INTER + skoff;
    const size_t gB1 = (size_t)(colBase + c1 * 16 + srow) * INTER + skoff;

    for (int k0 = 0; k0 < INTER; k0 += 32) {
        gload_lds16(A + gA0 + k0, sA + c0 * 512);
        gload_lds16(A + gA1 + k0, sA + c1 * 512);
        gload_lds16(Bd + gB0 + k0, sB + c0 * 512);
        gload_lds16(Bd + gB1 + k0, sB + c1 * 512);
        asm volatile("s_waitcnt vmcnt(0)" ::: "memory");
        __syncthreads();

        s16x8 a[4], b[4];
#pragma unroll
        for (int mf = 0; mf < 4; ++mf)
            a[mf] = *(const s16x8*)&sA[(wr * 64 + mf * 16) * 32 + rA];
#pragma unroll
        for (int nf = 0; nf < 4; ++nf)
            b[nf] = *(const s16x8*)&sB[(wc * 64 + nf * 16) * 32 + rA];
#pragma unroll
        for (int mf = 0; mf < 4; ++mf)
#pragma unroll
            for (int nf = 0; nf < 4; ++nf)
                acc[mf][nf] = __builtin_amdgcn_mfma_f32_16x16x32_bf16(a[mf], b[nf], acc[mf][nf], 0, 0, 0);
        __syncthreads();
    }

#pragma unroll
    for (int mf = 0; mf < 4; ++mf)
#pragma unroll
        for (int j = 0; j < 4; ++j) {
            int slot = slot0 + wr * 64 + mf * 16 + (lane >> 4) * 4 + j;
#pragma unroll
            for (int nf = 0; nf < 4; ++nf) {
                int c = colBase + wc * 64 + nf * 16 + (lane & 15);
                y[(size_t)slot * DDIM + c] = f2bf(acc[mf][nf][j]);
            }
        }
}

// out[t][c] = w0 * y[sl0][c] + w1 * y[sl1][c]; y is bf16, out f32
__global__ __launch_bounds__(256) void combine_kernel(
    const unsigned short* __restrict__ y,
    const int2* __restrict__ tslot,
    const float2* __restrict__ wpair,
    float* __restrict__ out) {
    int gid = blockIdx.x * 256 + threadIdx.x;  // 0 .. 8192*128-1
    int tok = gid >> 7;
    int c8 = (gid & 127) * 8;
    int2 ts = tslot[tok];
    float2 w = wpair[tok];
    u16x8 a = *(const u16x8*)(y + (size_t)ts.x * DDIM + c8);
    u16x8 b = *(const u16x8*)(y + (size_t)ts.y * DDIM + c8);
    float4 r0, r1;
    r0.x = w.x * bf2f(a[0]) + w.y * bf2f(b[0]);
    r0.y = w.x * bf2f(a[1]) + w.y * bf2f(b[1]);
    r0.z = w.x * bf2f(a[2]) + w.y * bf2f(b[2]);
    r0.w = w.x * bf2f(a[3]) + w.y * bf2f(b[3]);
    r1.x = w.x * bf2f(a[4]) + w.y * bf2f(b[4]);
    r1.y = w.x * bf2f(a[5]) + w.y * bf2f(b[5]);
    r1.z = w.x * bf2f(a[6]) + w.y * bf2f(b[6]);
    r1.w = w.x * bf2f(a[7]) + w.y * bf2f(b[7]);
    float* op = out + (size_t)tok * DDIM + c8;
    *(float4*)op = r0;
    *(float4*)(op + 4) = r1;
}

// ---------------- host ----------------

extern "C" void kernel_launch(void* const* d_in, const int* in_sizes, int n_in,
                              void* d_out, int out_size, void* d_ws, size_t ws_size,
                              hipStream_t stream) {
    const float* h = (const float*)d_in[0];
    const float* gate_w = (const float*)d_in[1];
    const float* wg = (const float*)d_in[2];
    const float* wu = (const float*)d_in[3];
    const float* wd = (const float*)d_in[4];

    float* out = (float*)d_out;                       // results: 8192*1024
    float* lb = out + (size_t)B_TOK * DDIM;           // 1
    float* route = lb + 1;                            // 8192*8

    const size_t SZ_META = 1 << 20;                           // 1 MiB
    const size_t SZ_HB = (size_t)B_TOK * DDIM * 2;            // 16,777,216
    const size_t SZ_W = (size_t)NEXP * DDIM * INTER * 2;      // 46,137,344 per tensor
    const size_t SZ_ACT = (size_t)CAP_SLOTS * INTER * 2;      // 98,041,856
    const size_t NEED = SZ_META + SZ_HB + 2 * SZ_W + SZ_ACT;  // ~198.5 MiB
    if (ws_size < NEED) {
        fprintf(stderr, "kernel_launch: ws too small: %zu < %zu\n", ws_size, NEED);
        return;
    }
    char* ws = (char*)d_ws;
    // meta layout (within first 1 MiB)
    int* counts = (int*)(ws + 0);            // 8
    int* rank = (int*)(ws + 32);             // 8
    int* aoff = (int*)(ws + 64);             // 8
    float* sums = (float*)(ws + 96);         // 8
    int* tile_e = (int*)(ws + 128);          // 136
    int* tile_s0 = (int*)(ws + 1024);        // 136
    int* sel01 = (int*)(ws + 2048);          // 8192
    float2* wpair = (float2*)(ws + 34816);   // 8192
    int* idx = (int*)(ws + 100352);          // 17408
    int2* tslot = (int2*)(ws + 262144);      // 8192 int2 = 64KB

    unsigned short* hb = (unsigned short*)(ws + SZ_META);
    unsigned short* wgT = (unsigned short*)(ws + SZ_META + SZ_HB);
    unsigned short* wuT = (unsigned short*)(ws + SZ_META + SZ_HB + SZ_W);
    unsigned short* act = (unsigned short*)(ws + SZ_META + SZ_HB + 2 * SZ_W);
    unsigned short* wdT = wgT;                               // reuse wgT space AFTER gemm1
    unsigned short* y = wuT;                                 // reuse wuT space AFTER gemm1 (35.6MB < 44MB)

    hipMemsetAsync(ws, 0, SZ_META, stream);

    transpose_convert_v2<<<dim3(INTER / 64, DDIM / 64, NEXP), 256, 0, stream>>>(wg, wgT, DDIM, INTER);
    transpose_convert_v2<<<dim3(INTER / 64, DDIM / 64, NEXP), 256, 0, stream>>>(wu, wuT, DDIM, INTER);

    gating_kernel<<<B_TOK / 4, 256, 0, stream>>>(h, gate_w, route, sel01, wpair, counts, sums, hb);
    setup_kernel<<<1, 256, 0, stream>>>(counts, sums, aoff, tile_e, tile_s0, lb);
    fill_kernel<<<B_TOK / 256, 256, 0, stream>>>(sel01, aoff, rank, idx, tslot);

    // gemm1 split into two half-N dispatches (same work, profiler visibility)
    gemm1_sparse<<<dim3(CAP_TILES, 11), 256, 0, stream>>>(
        hb, wgT, wuT, tile_e, tile_s0, idx, act, 0);
    gemm1_sparse<<<dim3(CAP_TILES, 11), 256, 0, stream>>>(
        hb, wgT, wuT, tile_e, tile_s0, idx, act, 11);

    // now wgT/wuT are dead: transpose wd into wgT's space; y reuses wuT's space
    transpose_convert_v2<<<dim3(DDIM / 64, INTER / 64, NEXP), 256, 0, stream>>>(wd, wdT, INTER, DDIM);

    gemm2_sparse_v3<<<dim3(CAP_TILES, DDIM / 128), 256, 0, stream>>>(
        act, wdT, tile_e, tile_s0, y);

    combine_kernel<<<(B_TOK * 128) / 256, 256, 0, stream>>>(y, tslot, wpair, out);
}

// Round 9
// 527.014 us; speedup vs baseline: 1.5434x; 1.5233x over previous
//
#include <hip/hip_runtime.h>
#include <hip/hip_bf16.h>
#include <cstdio>

typedef short s16x8 __attribute__((ext_vector_type(8)));
typedef unsigned short u16x8 __attribute__((ext_vector_type(8)));
typedef float f32x4 __attribute__((ext_vector_type(4)));

#define B_TOK 8192      // b*l
#define DDIM 1024
#define INTER 2816
#define NEXP 8
#define CAP_TILES 136               // max sum ceil(cnt[e]/128) = 135; capacity 136
#define CAP_SLOTS (CAP_TILES * 128) // 17408

__device__ __forceinline__ unsigned short f2bf(float f) {
    unsigned int u = __float_as_uint(f);
    unsigned int r = u + 0x7fffu + ((u >> 16) & 1u);
    return (unsigned short)(r >> 16);
}

__device__ __forceinline__ float bf2f(unsigned short u) {
    unsigned int x = ((unsigned int)u) << 16;
    return __uint_as_float(x);
}

__device__ __forceinline__ void gload_lds16(const void* g, void* l) {
    __builtin_amdgcn_global_load_lds(
        (const __attribute__((address_space(1))) unsigned int*)g,
        (__attribute__((address_space(3))) unsigned int*)l, 16, 0, 0);
}

// ---------------- transpose+convert ----------------
// src: K x N f32 row-major (per expert via z), dst: N x K bf16. 64x64 tiles.
__global__ __launch_bounds__(256) void transpose_convert_v2(
    const float* __restrict__ src, unsigned short* __restrict__ dst,
    int K, int N) {
    __shared__ unsigned short tile[64][70];
    int e = blockIdx.z;
    src += (size_t)e * K * N;
    dst += (size_t)e * K * N;
    int n0 = blockIdx.x * 64, k0 = blockIdx.y * 64;
    int t = threadIdx.x;
    int lr = t >> 4;          // 0..15
    int lc = (t & 15) * 4;    // 0..60
#pragma unroll
    for (int p = 0; p < 4; ++p) {
        int kl = p * 16 + lr;
        float4 v = *(const float4*)(src + (size_t)(k0 + kl) * N + n0 + lc);
        tile[kl][lc + 0] = f2bf(v.x);
        tile[kl][lc + 1] = f2bf(v.y);
        tile[kl][lc + 2] = f2bf(v.z);
        tile[kl][lc + 3] = f2bf(v.w);
    }
    __syncthreads();
    int sn = t >> 3;          // 0..31
    int sk = (t & 7) * 8;     // 0..56
#pragma unroll
    for (int p = 0; p < 2; ++p) {
        int nl = p * 32 + sn;
        u16x8 o;
#pragma unroll
        for (int j = 0; j < 8; ++j) o[j] = tile[sk + j][nl];
        *(u16x8*)(dst + (size_t)(n0 + nl) * K + k0 + sk) = o;
    }
}

// ---------------- gating v2: grid-stride, LDS-aggregated counts/sums ----------
// 256 blocks x 256 thr; each wave handles 8 tokens. Global atomics: 16/block.
__global__ __launch_bounds__(256) void gating_kernel(
    const float* __restrict__ h,
    const float* __restrict__ gw,
    float* __restrict__ route,
    int* __restrict__ sel01,
    float2* __restrict__ wpair,
    int* __restrict__ counts,
    float* __restrict__ sums,
    unsigned short* __restrict__ hb) {
    __shared__ int lcnt[8];
    __shared__ float lsum[8];
    const int tid = threadIdx.x;
    if (tid < 8) { lcnt[tid] = 0; lsum[tid] = 0.f; }
    __syncthreads();
    const int wid = tid >> 6, lane = tid & 63;

    for (int t0 = 0; t0 < B_TOK; t0 += 1024) {
        int t = t0 + blockIdx.x * 4 + wid;
        const float* hp = h + (size_t)t * DDIM + lane * 16;
        float4 hv[4];
#pragma unroll
        for (int p = 0; p < 4; ++p) hv[p] = ((const float4*)hp)[p];

        u16x8 o0, o1;
        o0[0] = f2bf(hv[0].x); o0[1] = f2bf(hv[0].y); o0[2] = f2bf(hv[0].z); o0[3] = f2bf(hv[0].w);
        o0[4] = f2bf(hv[1].x); o0[5] = f2bf(hv[1].y); o0[6] = f2bf(hv[1].z); o0[7] = f2bf(hv[1].w);
        o1[0] = f2bf(hv[2].x); o1[1] = f2bf(hv[2].y); o1[2] = f2bf(hv[2].z); o1[3] = f2bf(hv[2].w);
        o1[4] = f2bf(hv[3].x); o1[5] = f2bf(hv[3].y); o1[6] = f2bf(hv[3].z); o1[7] = f2bf(hv[3].w);
        unsigned short* hbp = hb + (size_t)t * DDIM + lane * 16;
        *(u16x8*)hbp = o0;
        *(u16x8*)(hbp + 8) = o1;

        const float4* gp4 = (const float4*)(gw + (size_t)lane * 16 * NEXP);
        float s[8] = {0, 0, 0, 0, 0, 0, 0, 0};
#pragma unroll
        for (int p = 0; p < 4; ++p) {
#pragma unroll
            for (int q = 0; q < 4; ++q) {
                int kk = p * 4 + q;
                float hvk = (q == 0) ? hv[p].x : (q == 1) ? hv[p].y : (q == 2) ? hv[p].z : hv[p].w;
                float4 a = gp4[kk * 2], b = gp4[kk * 2 + 1];
                s[0] += hvk * a.x; s[1] += hvk * a.y; s[2] += hvk * a.z; s[3] += hvk * a.w;
                s[4] += hvk * b.x; s[5] += hvk * b.y; s[6] += hvk * b.z; s[7] += hvk * b.w;
            }
        }
#pragma unroll
        for (int off = 32; off > 0; off >>= 1) {
#pragma unroll
            for (int e = 0; e < 8; ++e) s[e] += __shfl_down(s[e], off);
        }
        if (lane == 0) {
            float m0 = -1e30f; int i0 = 0;
#pragma unroll
            for (int e = 0; e < 8; ++e) if (s[e] > m0) { m0 = s[e]; i0 = e; }
            float m1 = -1e30f; int i1 = -1;
#pragma unroll
            for (int e = 0; e < 8; ++e) if (e != i0 && s[e] > m1) { m1 = s[e]; i1 = e; }
            float d = __expf(m1 - m0);
            float w0 = 1.f / (1.f + d);
            float w1 = d * w0;
#pragma unroll
            for (int e = 0; e < 8; ++e)
                route[(size_t)t * 8 + e] = (e == i0) ? w0 : ((e == i1) ? w1 : 0.f);
            sel01[t] = i0 | (i1 << 8);
            wpair[t] = make_float2(w0, w1);
            atomicAdd(&lcnt[i0], 1);
            atomicAdd(&lcnt[i1], 1);
            atomicAdd(&lsum[i0], w0);
            atomicAdd(&lsum[i1], w1);
        }
    }
    __syncthreads();
    if (tid < 8) {
        atomicAdd(&counts[tid], lcnt[tid]);
        atomicAdd(&sums[tid], lsum[tid]);
    }
}

// single block: per-expert 128-aligned slot offsets + tile table + lb_loss finalize
__global__ void setup_kernel(const int* __restrict__ counts,
                             const float* __restrict__ sums,
                             int* __restrict__ aoff,
                             int* __restrict__ tile_e,
                             int* __restrict__ tile_s0,
                             float* __restrict__ lb) {
    __shared__ int s_aoff[8], s_t0[9];
    if (threadIdx.x == 0) {
        int acc_slot = 0, acc_tile = 0;
        for (int e = 0; e < 8; ++e) {
            s_aoff[e] = acc_slot;
            s_t0[e] = acc_tile;
            int nt = (counts[e] + 127) >> 7;
            acc_slot += nt << 7;
            acc_tile += nt;
        }
        s_t0[8] = acc_tile;
        for (int e = 0; e < 8; ++e) aoff[e] = s_aoff[e];
        float acc = 0.f;
        for (int e = 0; e < 8; ++e) {
            float p = sums[e] / (float)B_TOK;
            acc += p * p;
        }
        lb[0] = 0.01f * acc;
    }
    __syncthreads();
    int t = threadIdx.x;
    if (t < CAP_TILES) {
        int e = -1, s0 = 0;
        for (int x = 0; x < 8; ++x)
            if (t >= s_t0[x] && t < s_t0[x + 1]) { e = x; s0 = s_aoff[x] + ((t - s_t0[x]) << 7); }
        tile_e[t] = e;
        tile_s0[t] = s0;
    }
}

// fill v2: per-block LDS ranks + one block-reservation atomic per expert.
// Slot assignment order differs from v1 but y-row contents are per-token,
// so final output is bitwise unchanged.
__global__ __launch_bounds__(256) void fill_kernel(
    const int* __restrict__ sel01,
    const int* __restrict__ aoff,
    int* __restrict__ rank,
    int* __restrict__ idx,
    int2* __restrict__ tslot) {
    __shared__ int lcnt[8], lbase[8];
    const int tid = threadIdx.x;
    if (tid < 8) lcnt[tid] = 0;
    __syncthreads();
    int t = blockIdx.x * 256 + tid;
    int s = sel01[t];
    int e0 = s & 0xff, e1 = (s >> 8) & 0xff;
    int lr0 = atomicAdd(&lcnt[e0], 1);
    int lr1 = atomicAdd(&lcnt[e1], 1);
    __syncthreads();
    if (tid < 8) lbase[tid] = atomicAdd(&rank[tid], lcnt[tid]);
    __syncthreads();
    int sl0 = aoff[e0] + lbase[e0] + lr0;
    int sl1 = aoff[e1] + lbase[e1] + lr1;
    idx[sl0] = t;
    idx[sl1] = t;
    tslot[t] = make_int2(sl0, sl1);
}

// ---------------- GEMM1 sparse: gathered rows, g/u dual, fused silu ----------------
// colOff splits the N dimension across two dispatches (profiler visibility).
__global__ __launch_bounds__(256, 2) void gemm1_sparse(
    const unsigned short* __restrict__ A,
    const unsigned short* __restrict__ Bg,
    const unsigned short* __restrict__ Bu,
    const int* __restrict__ tile_e,
    const int* __restrict__ tile_s0,
    const int* __restrict__ idx,
    unsigned short* __restrict__ act,
    int colOff) {
    int e = tile_e[blockIdx.x];
    if (e < 0) return;
    const int slot0 = tile_s0[blockIdx.x];
    Bg += (size_t)e * DDIM * INTER;
    Bu += (size_t)e * DDIM * INTER;

    __shared__ unsigned short sA[128 * 32];
    __shared__ unsigned short sG[128 * 32];
    __shared__ unsigned short sU[128 * 32];
    const int tid = threadIdx.x, wid = tid >> 6, lane = tid & 63;
    const int wr = wid >> 1, wc = wid & 1;
    const int colBase = (colOff + blockIdx.y) * 128;

    f32x4 accG[4][4], accU[4][4];
#pragma unroll
    for (int i = 0; i < 4; ++i)
#pragma unroll
        for (int j = 0; j < 4; ++j) { accG[i][j] = (f32x4)(0.f); accU[i][j] = (f32x4)(0.f); }

    const int c0 = wid, c1 = wid + 4;
    const int srow = lane >> 2;
    const int skoff = (lane & 3) * 8;
    const int rA = (lane & 15) * 32 + (lane >> 4) * 8;

    const size_t gA0 = (size_t)idx[slot0 + c0 * 16 + srow] * DDIM + skoff;
    const size_t gA1 = (size_t)idx[slot0 + c1 * 16 + srow] * DDIM + skoff;
    const size_t gB0 = (size_t)(colBase + c0 * 16 + srow) * DDIM + skoff;
    const size_t gB1 = (size_t)(colBase + c1 * 16 + srow) * DDIM + skoff;

    for (int k0 = 0; k0 < DDIM; k0 += 32) {
        gload_lds16(A + gA0 + k0, sA + c0 * 512);
        gload_lds16(A + gA1 + k0, sA + c1 * 512);
        gload_lds16(Bg + gB0 + k0, sG + c0 * 512);
        gload_lds16(Bg + gB1 + k0, sG + c1 * 512);
        gload_lds16(Bu + gB0 + k0, sU + c0 * 512);
        gload_lds16(Bu + gB1 + k0, sU + c1 * 512);
        asm volatile("s_waitcnt vmcnt(0)" ::: "memory");
        __syncthreads();

        s16x8 a[4], bg[4], bu[4];
#pragma unroll
        for (int mf = 0; mf < 4; ++mf)
            a[mf] = *(const s16x8*)&sA[(wr * 64 + mf * 16) * 32 + rA];
#pragma unroll
        for (int nf = 0; nf < 4; ++nf) {
            bg[nf] = *(const s16x8*)&sG[(wc * 64 + nf * 16) * 32 + rA];
            bu[nf] = *(const s16x8*)&sU[(wc * 64 + nf * 16) * 32 + rA];
        }
#pragma unroll
        for (int mf = 0; mf < 4; ++mf)
#pragma unroll
            for (int nf = 0; nf < 4; ++nf) {
                accG[mf][nf] = __builtin_amdgcn_mfma_f32_16x16x32_bf16(a[mf], bg[nf], accG[mf][nf], 0, 0, 0);
                accU[mf][nf] = __builtin_amdgcn_mfma_f32_16x16x32_bf16(a[mf], bu[nf], accU[mf][nf], 0, 0, 0);
            }
        __syncthreads();
    }

#pragma unroll
    for (int mf = 0; mf < 4; ++mf)
#pragma unroll
        for (int nf = 0; nf < 4; ++nf)
#pragma unroll
            for (int j = 0; j < 4; ++j) {
                int r = slot0 + wr * 64 + mf * 16 + (lane >> 4) * 4 + j;
                int c = colBase + wc * 64 + nf * 16 + (lane & 15);
                float g = accG[mf][nf][j], u = accU[mf][nf][j];
                float sg = 1.f / (1.f + __expf(-g));
                act[(size_t)r * INTER + c] = f2bf(g * sg * u);
            }
}

// ---------------- GEMM2 v3: act @ wdT full-width, slot-major bf16 output ----------------
__global__ __launch_bounds__(256, 3) void gemm2_sparse_v3(
    const unsigned short* __restrict__ A,
    const unsigned short* __restrict__ Bd,
    const int* __restrict__ tile_e,
    const int* __restrict__ tile_s0,
    unsigned short* __restrict__ y) {
    int e = tile_e[blockIdx.x];
    if (e < 0) return;
    const int slot0 = tile_s0[blockIdx.x];
    const int colBase = blockIdx.y * 128;
    Bd += (size_t)e * DDIM * INTER;

    __shared__ unsigned short sA[128 * 32];
    __shared__ unsigned short sB[128 * 32];
    const int tid = threadIdx.x, wid = tid >> 6, lane = tid & 63;
    const int wr = wid >> 1, wc = wid & 1;

    f32x4 acc[4][4];
#pragma unroll
    for (int i = 0; i < 4; ++i)
#pragma unroll
        for (int j = 0; j < 4; ++j) acc[i][j] = (f32x4)(0.f);

    const int c0 = wid, c1 = wid + 4;
    const int srow = lane >> 2;
    const int skoff = (lane & 3) * 8;
    const int rA = (lane & 15) * 32 + (lane >> 4) * 8;

    const size_t gA0 = (size_t)(slot0 + c0 * 16 + srow) * INTER + skoff;
    const size_t gA1 = (size_t)(slot0 + c1 * 16 + srow) * INTER + skoff;
    const size_t gB0 = (size_t)(colBase + c0 * 16 + srow) * INTER + skoff;
    const size_t gB1 = (size_t)(colBase + c1 * 16 + srow) * INTER + skoff;

    for (int k0 = 0; k0 < INTER; k0 += 32) {
        gload_lds16(A + gA0 + k0, sA + c0 * 512);
        gload_lds16(A + gA1 + k0, sA + c1 * 512);
        gload_lds16(Bd + gB0 + k0, sB + c0 * 512);
        gload_lds16(Bd + gB1 + k0, sB + c1 * 512);
        asm volatile("s_waitcnt vmcnt(0)" ::: "memory");
        __syncthreads();

        s16x8 a[4], b[4];
#pragma unroll
        for (int mf = 0; mf < 4; ++mf)
            a[mf] = *(const s16x8*)&sA[(wr * 64 + mf * 16) * 32 + rA];
#pragma unroll
        for (int nf = 0; nf < 4; ++nf)
            b[nf] = *(const s16x8*)&sB[(wc * 64 + nf * 16) * 32 + rA];
#pragma unroll
        for (int mf = 0; mf < 4; ++mf)
#pragma unroll
            for (int nf = 0; nf < 4; ++nf)
                acc[mf][nf] = __builtin_amdgcn_mfma_f32_16x16x32_bf16(a[mf], b[nf], acc[mf][nf], 0, 0, 0);
        __syncthreads();
    }

#pragma unroll
    for (int mf = 0; mf < 4; ++mf)
#pragma unroll
        for (int j = 0; j < 4; ++j) {
            int slot = slot0 + wr * 64 + mf * 16 + (lane >> 4) * 4 + j;
#pragma unroll
            for (int nf = 0; nf < 4; ++nf) {
                int c = colBase + wc * 64 + nf * 16 + (lane & 15);
                y[(size_t)slot * DDIM + c] = f2bf(acc[mf][nf][j]);
            }
        }
}

// out[t][c] = w0 * y[sl0][c] + w1 * y[sl1][c]; y is bf16, out f32
__global__ __launch_bounds__(256) void combine_kernel(
    const unsigned short* __restrict__ y,
    const int2* __restrict__ tslot,
    const float2* __restrict__ wpair,
    float* __restrict__ out) {
    int gid = blockIdx.x * 256 + threadIdx.x;  // 0 .. 8192*128-1
    int tok = gid >> 7;
    int c8 = (gid & 127) * 8;
    int2 ts = tslot[tok];
    float2 w = wpair[tok];
    u16x8 a = *(const u16x8*)(y + (size_t)ts.x * DDIM + c8);
    u16x8 b = *(const u16x8*)(y + (size_t)ts.y * DDIM + c8);
    float4 r0, r1;
    r0.x = w.x * bf2f(a[0]) + w.y * bf2f(b[0]);
    r0.y = w.x * bf2f(a[1]) + w.y * bf2f(b[1]);
    r0.z = w.x * bf2f(a[2]) + w.y * bf2f(b[2]);
    r0.w = w.x * bf2f(a[3]) + w.y * bf2f(b[3]);
    r1.x = w.x * bf2f(a[4]) + w.y * bf2f(b[4]);
    r1.y = w.x * bf2f(a[5]) + w.y * bf2f(b[5]);
    r1.z = w.x * bf2f(a[6]) + w.y * bf2f(b[6]);
    r1.w = w.x * bf2f(a[7]) + w.y * bf2f(b[7]);
    float* op = out + (size_t)tok * DDIM + c8;
    *(float4*)op = r0;
    *(float4*)(op + 4) = r1;
}

// ---------------- host ----------------

extern "C" void kernel_launch(void* const* d_in, const int* in_sizes, int n_in,
                              void* d_out, int out_size, void* d_ws, size_t ws_size,
                              hipStream_t stream) {
    const float* h = (const float*)d_in[0];
    const float* gate_w = (const float*)d_in[1];
    const float* wg = (const float*)d_in[2];
    const float* wu = (const float*)d_in[3];
    const float* wd = (const float*)d_in[4];

    float* out = (float*)d_out;                       // results: 8192*1024
    float* lb = out + (size_t)B_TOK * DDIM;           // 1
    float* route = lb + 1;                            // 8192*8

    const size_t SZ_META = 1 << 20;                           // 1 MiB
    const size_t SZ_HB = (size_t)B_TOK * DDIM * 2;            // 16,777,216
    const size_t SZ_W = (size_t)NEXP * DDIM * INTER * 2;      // 46,137,344 per tensor
    const size_t SZ_ACT = (size_t)CAP_SLOTS * INTER * 2;      // 98,041,856
    const size_t NEED = SZ_META + SZ_HB + 2 * SZ_W + SZ_ACT;  // ~198.5 MiB
    if (ws_size < NEED) {
        fprintf(stderr, "kernel_launch: ws too small: %zu < %zu\n", ws_size, NEED);
        return;
    }
    char* ws = (char*)d_ws;
    // meta layout (within first 1 MiB)
    int* counts = (int*)(ws + 0);            // 8
    int* rank = (int*)(ws + 32);             // 8
    int* aoff = (int*)(ws + 64);             // 8
    float* sums = (float*)(ws + 96);         // 8
    int* tile_e = (int*)(ws + 128);          // 136
    int* tile_s0 = (int*)(ws + 1024);        // 136
    int* sel01 = (int*)(ws + 2048);          // 8192
    float2* wpair = (float2*)(ws + 34816);   // 8192
    int* idx = (int*)(ws + 100352);          // 17408
    int2* tslot = (int2*)(ws + 262144);      // 8192 int2 = 64KB

    unsigned short* hb = (unsigned short*)(ws + SZ_META);
    unsigned short* wgT = (unsigned short*)(ws + SZ_META + SZ_HB);
    unsigned short* wuT = (unsigned short*)(ws + SZ_META + SZ_HB + SZ_W);
    unsigned short* act = (unsigned short*)(ws + SZ_META + SZ_HB + 2 * SZ_W);
    unsigned short* wdT = wgT;                               // reuse wgT space AFTER gemm1
    unsigned short* y = wuT;                                 // reuse wuT space AFTER gemm1 (35.6MB < 44MB)

    hipMemsetAsync(ws, 0, SZ_META, stream);

    transpose_convert_v2<<<dim3(INTER / 64, DDIM / 64, NEXP), 256, 0, stream>>>(wg, wgT, DDIM, INTER);
    transpose_convert_v2<<<dim3(INTER / 64, DDIM / 64, NEXP), 256, 0, stream>>>(wu, wuT, DDIM, INTER);

    gating_kernel<<<256, 256, 0, stream>>>(h, gate_w, route, sel01, wpair, counts, sums, hb);
    setup_kernel<<<1, 256, 0, stream>>>(counts, sums, aoff, tile_e, tile_s0, lb);
    fill_kernel<<<B_TOK / 256, 256, 0, stream>>>(sel01, aoff, rank, idx, tslot);

    // gemm1 split into two half-N dispatches (same work, profiler visibility)
    gemm1_sparse<<<dim3(CAP_TILES, 11), 256, 0, stream>>>(
        hb, wgT, wuT, tile_e, tile_s0, idx, act, 0);
    gemm1_sparse<<<dim3(CAP_TILES, 11), 256, 0, stream>>>(
        hb, wgT, wuT, tile_e, tile_s0, idx, act, 11);

    // now wgT/wuT are dead: transpose wd into wgT's space; y reuses wuT's space
    transpose_convert_v2<<<dim3(DDIM / 64, INTER / 64, NEXP), 256, 0, stream>>>(wd, wdT, INTER, DDIM);

    gemm2_sparse_v3<<<dim3(CAP_TILES, DDIM / 128), 256, 0, stream>>>(
        act, wdT, tile_e, tile_s0, y);

    combine_kernel<<<(B_TOK * 128) / 256, 256, 0, stream>>>(y, tslot, wpair, out);
}

// Round 10
// 511.948 us; speedup vs baseline: 1.5888x; 1.0294x over previous
//
#include <hip/hip_runtime.h>
#include <hip/hip_bf16.h>
#include <cstdio>

typedef short s16x8 __attribute__((ext_vector_type(8)));
typedef unsigned short u16x8 __attribute__((ext_vector_type(8)));
typedef float f32x4 __attribute__((ext_vector_type(4)));

#define B_TOK 8192      // b*l
#define DDIM 1024
#define INTER 2816
#define NEXP 8
#define CAP_TILES 136               // max sum ceil(cnt[e]/128) = 135; capacity 136
#define CAP_SLOTS (CAP_TILES * 128) // 17408

__device__ __forceinline__ unsigned short f2bf(float f) {
    unsigned int u = __float_as_uint(f);
    unsigned int r = u + 0x7fffu + ((u >> 16) & 1u);
    return (unsigned short)(r >> 16);
}

__device__ __forceinline__ float bf2f(unsigned short u) {
    unsigned int x = ((unsigned int)u) << 16;
    return __uint_as_float(x);
}

__device__ __forceinline__ void gload_lds16(const void* g, void* l) {
    __builtin_amdgcn_global_load_lds(
        (const __attribute__((address_space(1))) unsigned int*)g,
        (__attribute__((address_space(3))) unsigned int*)l, 16, 0, 0);
}

// ---------------- transpose+convert ----------------
// src: K x N f32 row-major (per expert via z), dst: N x K bf16. 64x64 tiles.
__global__ __launch_bounds__(256) void transpose_convert_v2(
    const float* __restrict__ src, unsigned short* __restrict__ dst,
    int K, int N) {
    __shared__ unsigned short tile[64][70];
    int e = blockIdx.z;
    src += (size_t)e * K * N;
    dst += (size_t)e * K * N;
    int n0 = blockIdx.x * 64, k0 = blockIdx.y * 64;
    int t = threadIdx.x;
    int lr = t >> 4;          // 0..15
    int lc = (t & 15) * 4;    // 0..60
#pragma unroll
    for (int p = 0; p < 4; ++p) {
        int kl = p * 16 + lr;
        float4 v = *(const float4*)(src + (size_t)(k0 + kl) * N + n0 + lc);
        tile[kl][lc + 0] = f2bf(v.x);
        tile[kl][lc + 1] = f2bf(v.y);
        tile[kl][lc + 2] = f2bf(v.z);
        tile[kl][lc + 3] = f2bf(v.w);
    }
    __syncthreads();
    int sn = t >> 3;          // 0..31
    int sk = (t & 7) * 8;     // 0..56
#pragma unroll
    for (int p = 0; p < 2; ++p) {
        int nl = p * 32 + sn;
        u16x8 o;
#pragma unroll
        for (int j = 0; j < 8; ++j) o[j] = tile[sk + j][nl];
        *(u16x8*)(dst + (size_t)(n0 + nl) * K + k0 + sk) = o;
    }
}

// ---------------- gating v2: grid-stride, LDS-aggregated counts/sums ----------
__global__ __launch_bounds__(256) void gating_kernel(
    const float* __restrict__ h,
    const float* __restrict__ gw,
    float* __restrict__ route,
    int* __restrict__ sel01,
    float2* __restrict__ wpair,
    int* __restrict__ counts,
    float* __restrict__ sums,
    unsigned short* __restrict__ hb) {
    __shared__ int lcnt[8];
    __shared__ float lsum[8];
    const int tid = threadIdx.x;
    if (tid < 8) { lcnt[tid] = 0; lsum[tid] = 0.f; }
    __syncthreads();
    const int wid = tid >> 6, lane = tid & 63;

    for (int t0 = 0; t0 < B_TOK; t0 += 1024) {
        int t = t0 + blockIdx.x * 4 + wid;
        const float* hp = h + (size_t)t * DDIM + lane * 16;
        float4 hv[4];
#pragma unroll
        for (int p = 0; p < 4; ++p) hv[p] = ((const float4*)hp)[p];

        u16x8 o0, o1;
        o0[0] = f2bf(hv[0].x); o0[1] = f2bf(hv[0].y); o0[2] = f2bf(hv[0].z); o0[3] = f2bf(hv[0].w);
        o0[4] = f2bf(hv[1].x); o0[5] = f2bf(hv[1].y); o0[6] = f2bf(hv[1].z); o0[7] = f2bf(hv[1].w);
        o1[0] = f2bf(hv[2].x); o1[1] = f2bf(hv[2].y); o1[2] = f2bf(hv[2].z); o1[3] = f2bf(hv[2].w);
        o1[4] = f2bf(hv[3].x); o1[5] = f2bf(hv[3].y); o1[6] = f2bf(hv[3].z); o1[7] = f2bf(hv[3].w);
        unsigned short* hbp = hb + (size_t)t * DDIM + lane * 16;
        *(u16x8*)hbp = o0;
        *(u16x8*)(hbp + 8) = o1;

        const float4* gp4 = (const float4*)(gw + (size_t)lane * 16 * NEXP);
        float s[8] = {0, 0, 0, 0, 0, 0, 0, 0};
#pragma unroll
        for (int p = 0; p < 4; ++p) {
#pragma unroll
            for (int q = 0; q < 4; ++q) {
                int kk = p * 4 + q;
                float hvk = (q == 0) ? hv[p].x : (q == 1) ? hv[p].y : (q == 2) ? hv[p].z : hv[p].w;
                float4 a = gp4[kk * 2], b = gp4[kk * 2 + 1];
                s[0] += hvk * a.x; s[1] += hvk * a.y; s[2] += hvk * a.z; s[3] += hvk * a.w;
                s[4] += hvk * b.x; s[5] += hvk * b.y; s[6] += hvk * b.z; s[7] += hvk * b.w;
            }
        }
#pragma unroll
        for (int off = 32; off > 0; off >>= 1) {
#pragma unroll
            for (int e = 0; e < 8; ++e) s[e] += __shfl_down(s[e], off);
        }
        if (lane == 0) {
            float m0 = -1e30f; int i0 = 0;
#pragma unroll
            for (int e = 0; e < 8; ++e) if (s[e] > m0) { m0 = s[e]; i0 = e; }
            float m1 = -1e30f; int i1 = -1;
#pragma unroll
            for (int e = 0; e < 8; ++e) if (e != i0 && s[e] > m1) { m1 = s[e]; i1 = e; }
            float d = __expf(m1 - m0);
            float w0 = 1.f / (1.f + d);
            float w1 = d * w0;
#pragma unroll
            for (int e = 0; e < 8; ++e)
                route[(size_t)t * 8 + e] = (e == i0) ? w0 : ((e == i1) ? w1 : 0.f);
            sel01[t] = i0 | (i1 << 8);
            wpair[t] = make_float2(w0, w1);
            atomicAdd(&lcnt[i0], 1);
            atomicAdd(&lcnt[i1], 1);
            atomicAdd(&lsum[i0], w0);
            atomicAdd(&lsum[i1], w1);
        }
    }
    __syncthreads();
    if (tid < 8) {
        atomicAdd(&counts[tid], lcnt[tid]);
        atomicAdd(&sums[tid], lsum[tid]);
    }
}

// single block: per-expert 128-aligned slot offsets + tile table + lb_loss finalize
__global__ void setup_kernel(const int* __restrict__ counts,
                             const float* __restrict__ sums,
                             int* __restrict__ aoff,
                             int* __restrict__ tile_e,
                             int* __restrict__ tile_s0,
                             float* __restrict__ lb) {
    __shared__ int s_aoff[8], s_t0[9];
    if (threadIdx.x == 0) {
        int acc_slot = 0, acc_tile = 0;
        for (int e = 0; e < 8; ++e) {
            s_aoff[e] = acc_slot;
            s_t0[e] = acc_tile;
            int nt = (counts[e] + 127) >> 7;
            acc_slot += nt << 7;
            acc_tile += nt;
        }
        s_t0[8] = acc_tile;
        for (int e = 0; e < 8; ++e) aoff[e] = s_aoff[e];
        float acc = 0.f;
        for (int e = 0; e < 8; ++e) {
            float p = sums[e] / (float)B_TOK;
            acc += p * p;
        }
        lb[0] = 0.01f * acc;
    }
    __syncthreads();
    int t = threadIdx.x;
    if (t < CAP_TILES) {
        int e = -1, s0 = 0;
        for (int x = 0; x < 8; ++x)
            if (t >= s_t0[x] && t < s_t0[x + 1]) { e = x; s0 = s_aoff[x] + ((t - s_t0[x]) << 7); }
        tile_e[t] = e;
        tile_s0[t] = s0;
    }
}

// fill v2: per-block LDS ranks + one block-reservation atomic per expert.
__global__ __launch_bounds__(256) void fill_kernel(
    const int* __restrict__ sel01,
    const int* __restrict__ aoff,
    int* __restrict__ rank,
    int* __restrict__ idx,
    int2* __restrict__ tslot) {
    __shared__ int lcnt[8], lbase[8];
    const int tid = threadIdx.x;
    if (tid < 8) lcnt[tid] = 0;
    __syncthreads();
    int t = blockIdx.x * 256 + tid;
    int s = sel01[t];
    int e0 = s & 0xff, e1 = (s >> 8) & 0xff;
    int lr0 = atomicAdd(&lcnt[e0], 1);
    int lr1 = atomicAdd(&lcnt[e1], 1);
    __syncthreads();
    if (tid < 8) lbase[tid] = atomicAdd(&rank[tid], lcnt[tid]);
    __syncthreads();
    int sl0 = aoff[e0] + lbase[e0] + lr0;
    int sl1 = aoff[e1] + lbase[e1] + lr1;
    idx[sl0] = t;
    idx[sl1] = t;
    tslot[t] = make_int2(sl0, sl1);
}

// ---------------- GEMM1 sparse: BK=64 (two 32-subtiles per barrier pair) -------
// gathered rows, g/u dual, fused silu. LDS 48KB -> 2 blocks/CU.
__global__ __launch_bounds__(256, 2) void gemm1_sparse(
    const unsigned short* __restrict__ A,
    const unsigned short* __restrict__ Bg,
    const unsigned short* __restrict__ Bu,
    const int* __restrict__ tile_e,
    const int* __restrict__ tile_s0,
    const int* __restrict__ idx,
    unsigned short* __restrict__ act) {
    int e = tile_e[blockIdx.x];
    if (e < 0) return;
    const int slot0 = tile_s0[blockIdx.x];
    Bg += (size_t)e * DDIM * INTER;
    Bu += (size_t)e * DDIM * INTER;

    __shared__ unsigned short sA[2][128 * 32];
    __shared__ unsigned short sG[2][128 * 32];
    __shared__ unsigned short sU[2][128 * 32];
    const int tid = threadIdx.x, wid = tid >> 6, lane = tid & 63;
    const int wr = wid >> 1, wc = wid & 1;
    const int colBase = blockIdx.y * 128;

    f32x4 accG[4][4], accU[4][4];
#pragma unroll
    for (int i = 0; i < 4; ++i)
#pragma unroll
        for (int j = 0; j < 4; ++j) { accG[i][j] = (f32x4)(0.f); accU[i][j] = (f32x4)(0.f); }

    const int c0 = wid, c1 = wid + 4;
    const int srow = lane >> 2;
    const int skoff = (lane & 3) * 8;
    const int rA = (lane & 15) * 32 + (lane >> 4) * 8;

    const size_t gA0 = (size_t)idx[slot0 + c0 * 16 + srow] * DDIM + skoff;
    const size_t gA1 = (size_t)idx[slot0 + c1 * 16 + srow] * DDIM + skoff;
    const size_t gB0 = (size_t)(colBase + c0 * 16 + srow) * DDIM + skoff;
    const size_t gB1 = (size_t)(colBase + c1 * 16 + srow) * DDIM + skoff;

    for (int k0 = 0; k0 < DDIM; k0 += 64) {
#pragma unroll
        for (int kk = 0; kk < 2; ++kk) {
            int k = k0 + kk * 32;
            gload_lds16(A + gA0 + k, sA[kk] + c0 * 512);
            gload_lds16(A + gA1 + k, sA[kk] + c1 * 512);
            gload_lds16(Bg + gB0 + k, sG[kk] + c0 * 512);
            gload_lds16(Bg + gB1 + k, sG[kk] + c1 * 512);
            gload_lds16(Bu + gB0 + k, sU[kk] + c0 * 512);
            gload_lds16(Bu + gB1 + k, sU[kk] + c1 * 512);
        }
        asm volatile("s_waitcnt vmcnt(0)" ::: "memory");
        __syncthreads();

#pragma unroll
        for (int kk = 0; kk < 2; ++kk) {
            s16x8 a[4], bg[4], bu[4];
#pragma unroll
            for (int mf = 0; mf < 4; ++mf)
                a[mf] = *(const s16x8*)&sA[kk][(wr * 64 + mf * 16) * 32 + rA];
#pragma unroll
            for (int nf = 0; nf < 4; ++nf) {
                bg[nf] = *(const s16x8*)&sG[kk][(wc * 64 + nf * 16) * 32 + rA];
                bu[nf] = *(const s16x8*)&sU[kk][(wc * 64 + nf * 16) * 32 + rA];
            }
#pragma unroll
            for (int mf = 0; mf < 4; ++mf)
#pragma unroll
                for (int nf = 0; nf < 4; ++nf) {
                    accG[mf][nf] = __builtin_amdgcn_mfma_f32_16x16x32_bf16(a[mf], bg[nf], accG[mf][nf], 0, 0, 0);
                    accU[mf][nf] = __builtin_amdgcn_mfma_f32_16x16x32_bf16(a[mf], bu[nf], accU[mf][nf], 0, 0, 0);
                }
        }
        __syncthreads();
    }

#pragma unroll
    for (int mf = 0; mf < 4; ++mf)
#pragma unroll
        for (int nf = 0; nf < 4; ++nf)
#pragma unroll
            for (int j = 0; j < 4; ++j) {
                int r = slot0 + wr * 64 + mf * 16 + (lane >> 4) * 4 + j;
                int c = colBase + wc * 64 + nf * 16 + (lane & 15);
                float g = accG[mf][nf][j], u = accU[mf][nf][j];
                float sg = 1.f / (1.f + __expf(-g));
                act[(size_t)r * INTER + c] = f2bf(g * sg * u);
            }
}

// ---------------- GEMM2 v4: BK=64 (two 32-subtiles per barrier pair) -----------
// act @ wdT full-width, slot-major bf16 output. LDS 32KB -> 3 blocks/CU.
__global__ __launch_bounds__(256, 3) void gemm2_sparse_v4(
    const unsigned short* __restrict__ A,
    const unsigned short* __restrict__ Bd,
    const int* __restrict__ tile_e,
    const int* __restrict__ tile_s0,
    unsigned short* __restrict__ y) {
    int e = tile_e[blockIdx.x];
    if (e < 0) return;
    const int slot0 = tile_s0[blockIdx.x];
    const int colBase = blockIdx.y * 128;
    Bd += (size_t)e * DDIM * INTER;

    __shared__ unsigned short sA[2][128 * 32];
    __shared__ unsigned short sB[2][128 * 32];
    const int tid = threadIdx.x, wid = tid >> 6, lane = tid & 63;
    const int wr = wid >> 1, wc = wid & 1;

    f32x4 acc[4][4];
#pragma unroll
    for (int i = 0; i < 4; ++i)
#pragma unroll
        for (int j = 0; j < 4; ++j) acc[i][j] = (f32x4)(0.f);

    const int c0 = wid, c1 = wid + 4;
    const int srow = lane >> 2;
    const int skoff = (lane & 3) * 8;
    const int rA = (lane & 15) * 32 + (lane >> 4) * 8;

    const size_t gA0 = (size_t)(slot0 + c0 * 16 + srow) * INTER + skoff;
    const size_t gA1 = (size_t)(slot0 + c1 * 16 + srow) * INTER + skoff;
    const size_t gB0 = (size_t)(colBase + c0 * 16 + srow) * INTER + skoff;
    const size_t gB1 = (size_t)(colBase + c1 * 16 + srow) * INTER + skoff;

    for (int k0 = 0; k0 < INTER; k0 += 64) {
#pragma unroll
        for (int kk = 0; kk < 2; ++kk) {
            int k = k0 + kk * 32;
            gload_lds16(A + gA0 + k, sA[kk] + c0 * 512);
            gload_lds16(A + gA1 + k, sA[kk] + c1 * 512);
            gload_lds16(Bd + gB0 + k, sB[kk] + c0 * 512);
            gload_lds16(Bd + gB1 + k, sB[kk] + c1 * 512);
        }
        asm volatile("s_waitcnt vmcnt(0)" ::: "memory");
        __syncthreads();

#pragma unroll
        for (int kk = 0; kk < 2; ++kk) {
            s16x8 a[4], b[4];
#pragma unroll
            for (int mf = 0; mf < 4; ++mf)
                a[mf] = *(const s16x8*)&sA[kk][(wr * 64 + mf * 16) * 32 + rA];
#pragma unroll
            for (int nf = 0; nf < 4; ++nf)
                b[nf] = *(const s16x8*)&sB[kk][(wc * 64 + nf * 16) * 32 + rA];
#pragma unroll
            for (int mf = 0; mf < 4; ++mf)
#pragma unroll
                for (int nf = 0; nf < 4; ++nf)
                    acc[mf][nf] = __builtin_amdgcn_mfma_f32_16x16x32_bf16(a[mf], b[nf], acc[mf][nf], 0, 0, 0);
        }
        __syncthreads();
    }

#pragma unroll
    for (int mf = 0; mf < 4; ++mf)
#pragma unroll
        for (int j = 0; j < 4; ++j) {
            int slot = slot0 + wr * 64 + mf * 16 + (lane >> 4) * 4 + j;
#pragma unroll
            for (int nf = 0; nf < 4; ++nf) {
                int c = colBase + wc * 64 + nf * 16 + (lane & 15);
                y[(size_t)slot * DDIM + c] = f2bf(acc[mf][nf][j]);
            }
        }
}

// out[t][c] = w0 * y[sl0][c] + w1 * y[sl1][c]; y is bf16, out f32
__global__ __launch_bounds__(256) void combine_kernel(
    const unsigned short* __restrict__ y,
    const int2* __restrict__ tslot,
    const float2* __restrict__ wpair,
    float* __restrict__ out) {
    int gid = blockIdx.x * 256 + threadIdx.x;  // 0 .. 8192*128-1
    int tok = gid >> 7;
    int c8 = (gid & 127) * 8;
    int2 ts = tslot[tok];
    float2 w = wpair[tok];
    u16x8 a = *(const u16x8*)(y + (size_t)ts.x * DDIM + c8);
    u16x8 b = *(const u16x8*)(y + (size_t)ts.y * DDIM + c8);
    float4 r0, r1;
    r0.x = w.x * bf2f(a[0]) + w.y * bf2f(b[0]);
    r0.y = w.x * bf2f(a[1]) + w.y * bf2f(b[1]);
    r0.z = w.x * bf2f(a[2]) + w.y * bf2f(b[2]);
    r0.w = w.x * bf2f(a[3]) + w.y * bf2f(b[3]);
    r1.x = w.x * bf2f(a[4]) + w.y * bf2f(b[4]);
    r1.y = w.x * bf2f(a[5]) + w.y * bf2f(b[5]);
    r1.z = w.x * bf2f(a[6]) + w.y * bf2f(b[6]);
    r1.w = w.x * bf2f(a[7]) + w.y * bf2f(b[7]);
    float* op = out + (size_t)tok * DDIM + c8;
    *(float4*)op = r0;
    *(float4*)(op + 4) = r1;
}

// ---------------- host ----------------

extern "C" void kernel_launch(void* const* d_in, const int* in_sizes, int n_in,
                              void* d_out, int out_size, void* d_ws, size_t ws_size,
                              hipStream_t stream) {
    const float* h = (const float*)d_in[0];
    const float* gate_w = (const float*)d_in[1];
    const float* wg = (const float*)d_in[2];
    const float* wu = (const float*)d_in[3];
    const float* wd = (const float*)d_in[4];

    float* out = (float*)d_out;                       // results: 8192*1024
    float* lb = out + (size_t)B_TOK * DDIM;           // 1
    float* route = lb + 1;                            // 8192*8

    const size_t SZ_META = 1 << 20;                           // 1 MiB
    const size_t SZ_HB = (size_t)B_TOK * DDIM * 2;            // 16,777,216
    const size_t SZ_W = (size_t)NEXP * DDIM * INTER * 2;      // 46,137,344 per tensor
    const size_t SZ_ACT = (size_t)CAP_SLOTS * INTER * 2;      // 98,041,856
    const size_t NEED = SZ_META + SZ_HB + 2 * SZ_W + SZ_ACT;  // ~198.5 MiB
    if (ws_size < NEED) {
        fprintf(stderr, "kernel_launch: ws too small: %zu < %zu\n", ws_size, NEED);
        return;
    }
    char* ws = (char*)d_ws;
    // meta layout (within first 1 MiB)
    int* counts = (int*)(ws + 0);            // 8
    int* rank = (int*)(ws + 32);             // 8
    int* aoff = (int*)(ws + 64);             // 8
    float* sums = (float*)(ws + 96);         // 8
    int* tile_e = (int*)(ws + 128);          // 136
    int* tile_s0 = (int*)(ws + 1024);        // 136
    int* sel01 = (int*)(ws + 2048);          // 8192
    float2* wpair = (float2*)(ws + 34816);   // 8192
    int* idx = (int*)(ws + 100352);          // 17408
    int2* tslot = (int2*)(ws + 262144);      // 8192 int2 = 64KB

    unsigned short* hb = (unsigned short*)(ws + SZ_META);
    unsigned short* wgT = (unsigned short*)(ws + SZ_META + SZ_HB);
    unsigned short* wuT = (unsigned short*)(ws + SZ_META + SZ_HB + SZ_W);
    unsigned short* act = (unsigned short*)(ws + SZ_META + SZ_HB + 2 * SZ_W);
    unsigned short* wdT = wgT;                               // reuse wgT space AFTER gemm1
    unsigned short* y = wuT;                                 // reuse wuT space AFTER gemm1 (35.6MB < 44MB)

    hipMemsetAsync(ws, 0, SZ_META, stream);

    transpose_convert_v2<<<dim3(INTER / 64, DDIM / 64, NEXP), 256, 0, stream>>>(wg, wgT, DDIM, INTER);
    transpose_convert_v2<<<dim3(INTER / 64, DDIM / 64, NEXP), 256, 0, stream>>>(wu, wuT, DDIM, INTER);

    gating_kernel<<<256, 256, 0, stream>>>(h, gate_w, route, sel01, wpair, counts, sums, hb);
    setup_kernel<<<1, 256, 0, stream>>>(counts, sums, aoff, tile_e, tile_s0, lb);
    fill_kernel<<<B_TOK / 256, 256, 0, stream>>>(sel01, aoff, rank, idx, tslot);

    gemm1_sparse<<<dim3(CAP_TILES, INTER / 128), 256, 0, stream>>>(
        hb, wgT, wuT, tile_e, tile_s0, idx, act);

    // now wgT/wuT are dead: transpose wd into wgT's space; y reuses wuT's space
    transpose_convert_v2<<<dim3(DDIM / 64, INTER / 64, NEXP), 256, 0, stream>>>(wd, wdT, INTER, DDIM);

    gemm2_sparse_v4<<<dim3(CAP_TILES, DDIM / 128), 256, 0, stream>>>(
        act, wdT, tile_e, tile_s0, y);

    combine_kernel<<<(B_TOK * 128) / 256, 256, 0, stream>>>(y, tslot, wpair, out);
}